// Round 15
// baseline (225.859 us; speedup 1.0000x reference)
//
#include <hip/hip_runtime.h>

typedef unsigned short u16;
typedef float f4v __attribute__((ext_vector_type(4)));
typedef short s8v __attribute__((ext_vector_type(8)));
typedef int   i4v __attribute__((ext_vector_type(4)));

#define SCALE_ 0.08838834764831845f
#define LOG2E_ 1.44269504088896340f

__device__ __forceinline__ u16 f2b(float f) {
    union { float f; unsigned u; } c; c.f = f;
    unsigned u = c.u + 0x7fffu + ((c.u >> 16) & 1u);
    return (u16)(u >> 16);
}

__device__ __forceinline__ s8v pack8(float4 a, float4 b) {
    s8v v;
    v[0] = (short)f2b(a.x); v[1] = (short)f2b(a.y);
    v[2] = (short)f2b(a.z); v[3] = (short)f2b(a.w);
    v[4] = (short)f2b(b.x); v[5] = (short)f2b(b.y);
    v[6] = (short)f2b(b.z); v[7] = (short)f2b(b.w);
    return v;
}

typedef const __attribute__((address_space(1))) unsigned int gu32;
typedef __attribute__((address_space(3))) unsigned int lu32;
__device__ __forceinline__ void glds16(const void* g, void* l) {
    __builtin_amdgcn_global_load_lds((gu32*)g, (lu32*)l, 16, 0, 0);
}

// K-row permutation for swapped-QK in-register PV fragments (R6-proven).
__device__ __forceinline__ int rho(int kv) {
    return (kv & 0x20) | ((kv & 0x04) << 2) | ((kv & 0x18) >> 1) | (kv & 3);
}

// ---------------------------------------------------------------------------
// Converter v4: 16kt x 16row LDS transposer. Phase 1: 256B-contiguous reads
// per thread (wave = 4x4KB runs) -> convert -> LDS in final swizzled row
// format (kt stride 2192B, row stride 136B: <=2-way banks). Phase 2: pure
// copy, 128B contiguous per thread (2KB per 16 lanes). Output byte-identical
// to the proven tiled layout [nt][64][RB][64] chunk-swizzled.
// ---------------------------------------------------------------------------
template <int RB>
__device__ __forceinline__ void tc_body(const float* __restrict__ srow0,
                                        u16* __restrict__ dst,
                                        int nt, int ktg, int rg, int K) {
    __shared__ __align__(16) char L[16 * 2192];
    const int t = threadIdx.x;
    {
        const int r = t >> 4, ktl = t & 15;
        const float* p = srow0 + (size_t)r * K + (ktg * 16 + ktl) * 64;
        char* lrow = L + ktl * 2192 + r * 136;
#pragma unroll
        for (int cc = 0; cc < 8; cc++) {
            float4 a = *(const float4*)(p + cc * 8);
            float4 b = *(const float4*)(p + cc * 8 + 4);
            *(s8v*)(lrow + ((cc ^ (r & 7)) * 16)) = pack8(a, b);
        }
    }
    __syncthreads();
    {
        const int ktl = t >> 4, r = t & 15;
        const char* lrow = L + ktl * 2192 + r * 136;
        u16* o = dst + ((size_t)(nt * 64 + ktg * 16 + ktl)) * (RB * 64) + (rg * 16 + r) * 64;
#pragma unroll
        for (int i = 0; i < 8; i++)
            *(i4v*)(o + i * 8) = *(const i4v*)(lrow + i * 16);
    }
}

template <int RB>
__global__ __launch_bounds__(256) void tc_k(const float* __restrict__ src,
                                            u16* __restrict__ dst, int K) {
    constexpr int RGM = RB / 16 - 1;          // 7 for 128, 3 for 64
    constexpr int RGS = (RB == 128) ? 3 : 2;
    const int bx = blockIdx.x, nt = blockIdx.y;
    const int rg = bx & RGM, ktg = bx >> RGS;
    tc_body<RB>(src + (size_t)(nt * RB + rg * 16) * K, dst, nt, ktg, rg, K);
}

// Concatenated Wq|Wk|Wv -> one N=6144 tiled buffer (RB=128).
__global__ __launch_bounds__(256) void tc3_k(const float* __restrict__ Wq,
                                             const float* __restrict__ Wk,
                                             const float* __restrict__ Wv,
                                             u16* __restrict__ dst) {
    const int bx = blockIdx.x, nt = blockIdx.y;
    const int rg = bx & 7, ktg = bx >> 3;
    const float* s;
    int ln;
    if (nt < 32)      { s = Wq; ln = nt; }
    else if (nt < 40) { s = Wk; ln = nt - 32; }
    else              { s = Wv; ln = nt - 40; }
    tc_body<128>(s + (size_t)(ln * 128 + rg * 16) * 4096, dst, nt, ktg, rg, 4096);
}

// ---------------------------------------------------------------------------
// GEMM v2 (R6-proven): 2-buffer dbuf, vmcnt(0)+__syncthreads, glds staging,
// XCD-chunked bijective swizzle (1D grid), split-K.
// ---------------------------------------------------------------------------
__global__ __launch_bounds__(256) void fgemm2(const u16* __restrict__ Ag,
                                              const u16* __restrict__ Bg,
                                              float* __restrict__ Cp,
                                              int M, int N, int K, int Ksl,
                                              int NY, int NZ) {
    __shared__ __align__(16) u16 As[2][4096];
    __shared__ __align__(16) u16 Bs[2][8192];
    const int tid = threadIdx.x, lane = tid & 63, wid = tid >> 6;
    const int lm = lane & 15, lg = lane >> 4;
    const int nb = gridDim.x, per = nb >> 3, w = blockIdx.x;
    const int idx = (w & 7) * per + (w >> 3);
    const int nx = idx / (NY * NZ);
    const int rem = idx - nx * (NY * NZ);
    const int my = rem % NY, z = rem / NY;
    const int m0 = my * 64, n0 = nx * 128;
    const int KT = K >> 6, NT = Ksl >> 6;
    const int kt0 = (z * Ksl) >> 6;
    const u16* ga = Ag + ((size_t)my * KT + kt0) * 4096;
    const u16* gb = Bg + ((size_t)nx * KT + kt0) * 8192;
    Cp += (size_t)z * M * N;

    f4v acc[4][2];
#pragma unroll
    for (int mi = 0; mi < 4; mi++)
#pragma unroll
        for (int ni = 0; ni < 2; ni++) acc[mi][ni] = (f4v){0.f, 0.f, 0.f, 0.f};

    auto STAGE = [&](int buf, int kt) {
        const char* a = (const char*)(ga + (size_t)kt * 4096) + tid * 16;
        const char* b = (const char*)(gb + (size_t)kt * 8192) + tid * 16;
        char* la = (char*)As[buf] + tid * 16;
        char* lb = (char*)Bs[buf] + tid * 16;
        glds16(a, la);
        glds16(a + 4096, la + 4096);
#pragma unroll
        for (int i = 0; i < 4; i++) glds16(b + i * 4096, lb + i * 4096);
    };

    STAGE(0, 0);
    asm volatile("s_waitcnt vmcnt(0)" ::: "memory");
    __syncthreads();

    for (int kt = 0; kt < NT; ++kt) {
        const int cur = kt & 1;
        if (kt + 1 < NT) STAGE(cur ^ 1, kt + 1);
#pragma unroll
        for (int ks = 0; ks < 2; ks++) {
            s8v av[4], bv[2];
#pragma unroll
            for (int mi = 0; mi < 4; mi++) {
                int r = mi * 16 + lm;
                av[mi] = *(const s8v*)(As[cur] + r * 64 + (((ks * 4 + lg) ^ (r & 7)) * 8));
            }
#pragma unroll
            for (int ni = 0; ni < 2; ni++) {
                int r = wid * 32 + ni * 16 + lm;
                bv[ni] = *(const s8v*)(Bs[cur] + r * 64 + (((ks * 4 + lg) ^ (r & 7)) * 8));
            }
#pragma unroll
            for (int mi = 0; mi < 4; mi++)
#pragma unroll
                for (int ni = 0; ni < 2; ni++)
                    acc[mi][ni] = __builtin_amdgcn_mfma_f32_16x16x32_bf16(av[mi], bv[ni], acc[mi][ni], 0, 0, 0);
        }
        asm volatile("s_waitcnt vmcnt(0)" ::: "memory");
        __syncthreads();
    }

#pragma unroll
    for (int mi = 0; mi < 4; mi++)
#pragma unroll
        for (int ni = 0; ni < 2; ni++)
#pragma unroll
            for (int r = 0; r < 4; r++) {
                int m = m0 + mi * 16 + lg * 4 + r;
                int n = n0 + wid * 32 + ni * 16 + lm;
                Cp[(size_t)m * N + n] = acc[mi][ni][r];
            }
}

// ---------------------------------------------------------------------------
// Fused epilogue over C[z][512][6144]: Q-norm+rope / K-norm+rope / V convert.
// ---------------------------------------------------------------------------
__global__ __launch_bounds__(256) void epi_k(const float* __restrict__ C,
                                             u16* __restrict__ qb,
                                             u16* __restrict__ kb,
                                             u16* __restrict__ vb,
                                             const float* __restrict__ qnw,
                                             const float* __restrict__ knw,
                                             const int* __restrict__ cseq) {
    const int lane = threadIdx.x & 63, w = threadIdx.x >> 6;
    const int blk = blockIdx.x;
    const size_t sls = (size_t)512 * 6144;

    if (blk < 4096) {           // ---- Q ----
        const int rid = blk * 4 + w;
        const int h = rid & 31, m = rid >> 5;
        const int s = m & 127, b = m >> 7;
        const float* p = C + (size_t)m * 6144 + h * 128;
        float x1 = p[lane] + p[sls + lane];
        float x2 = p[lane + 64] + p[sls + lane + 64];
        float ss = x1 * x1 + x2 * x2;
#pragma unroll
        for (int off = 1; off < 64; off <<= 1) ss += __shfl_xor(ss, off);
        float inv = rsqrtf(ss * (1.0f / 128.0f) + 1e-6f);
        float n1 = x1 * inv * qnw[lane];
        float n2 = x2 * inv * qnw[lane + 64];
        float pos = (float)(cseq[b] + s);
        float ang = pos * powf(10000.0f, -(float)lane * (1.0f / 64.0f));
        float cs = cosf(ang), sn = sinf(ang);
        const float osc = SCALE_ * LOG2E_;
        qb[(size_t)rid * 128 + lane]      = f2b((n1 * cs - n2 * sn) * osc);
        qb[(size_t)rid * 128 + lane + 64] = f2b((n2 * cs + n1 * sn) * osc);
    } else if (blk < 5120) {    // ---- K ----
        const int rid = (blk - 4096) * 4 + w;
        const int hk = rid & 7, m = rid >> 3;
        const int s = m & 127, b = m >> 7;
        const float* p = C + (size_t)m * 6144 + 4096 + hk * 128;
        float x1 = p[lane] + p[sls + lane];
        float x2 = p[lane + 64] + p[sls + lane + 64];
        float ss = x1 * x1 + x2 * x2;
#pragma unroll
        for (int off = 1; off < 64; off <<= 1) ss += __shfl_xor(ss, off);
        float inv = rsqrtf(ss * (1.0f / 128.0f) + 1e-6f);
        float n1 = x1 * inv * knw[lane];
        float n2 = x2 * inv * knw[lane + 64];
        float pos = (float)(cseq[b] + s);
        float ang = pos * powf(10000.0f, -(float)lane * (1.0f / 64.0f));
        float cs = cosf(ang), sn = sinf(ang);
        kb[(size_t)rid * 128 + lane]      = f2b(n1 * cs - n2 * sn);
        kb[(size_t)rid * 128 + lane + 64] = f2b(n2 * cs + n1 * sn);
    } else {                    // ---- V ----
        const int rid = (blk - 5120) * 4 + w;
        const int hk = rid & 7, m = rid >> 3;
        const float* p = C + (size_t)m * 6144 + 5120 + hk * 128;
        float x1 = p[lane] + p[sls + lane];
        float x2 = p[lane + 64] + p[sls + lane + 64];
        vb[(size_t)rid * 128 + lane]      = f2b(x1);
        vb[(size_t)rid * 128 + lane + 64] = f2b(x2);
    }
}

// Sum nsl K-slices -> fp32 out.
__global__ __launch_bounds__(256) void redN_k(const float* __restrict__ p,
                                              float* __restrict__ out, int n4,
                                              int nsl, size_t sls) {
    int i = blockIdx.x * blockDim.x + threadIdx.x;
    if (i < n4) {
        f4v s = (f4v){0.f, 0.f, 0.f, 0.f};
        for (int sl = 0; sl < nsl; sl++)
            s += *(const f4v*)(p + sl * sls + (size_t)i * 4);
        *(f4v*)(out + (size_t)i * 4) = s;
    }
}

// ---------------------------------------------------------------------------
// KV-cache -> bf16 MFMA-ready layouts (K rows rho-permuted). Unchanged (R6).
// ---------------------------------------------------------------------------
__global__ __launch_bounds__(256) void cvtkv_k(const float* __restrict__ kc,
                                               const float* __restrict__ vc,
                                               const u16* __restrict__ kb,
                                               const u16* __restrict__ vb,
                                               const int* __restrict__ btab,
                                               const int* __restrict__ cseq,
                                               u16* __restrict__ kb2,
                                               u16* __restrict__ vb2) {
    const int t = blockIdx.x, hk = blockIdx.y, b = blockIdx.z;
    const int tid = threadIdx.x;
    const int cl = cseq[b];
    if (t < 64 && t * 64 >= cl) return;
    u16* kout = kb2 + ((size_t)(b * 8 + hk) * 66 + t) * 8192;
    u16* vout = vb2 + ((size_t)(b * 8 + hk) * 66 + t) * 8192;

    if (t < 64) {
#pragma unroll
        for (int i = 0; i < 4; i++) {
            int c = tid + i * 256; int r = c >> 4, c16 = c & 15;
            int rs = rho(r);
            int cc = c16 ^ (rs & 7);
            int p = t * 64 + r;
            const float* src = kc + (((size_t)btab[b * 16 + (p >> 8)] * 256 + (p & 255)) * 8 + hk) * 128 + cc * 8;
            float4 f0 = *(const float4*)src, f1 = *(const float4*)(src + 4);
            *(s8v*)(kout + rs * 128 + c16 * 8) = pack8(f0, f1);
        }
#pragma unroll
        for (int i = 0; i < 4; i++) {
            int c = tid + i * 256; int pr = c >> 5, c16v = c & 31;
            int nc = c16v ^ pr;
            int n = nc * 4;
            int p = t * 64 + pr * 2;
            const float* s0 = vc + (((size_t)btab[b * 16 + (p >> 8)] * 256 + (p & 255)) * 8 + hk) * 128 + n;
            float4 e = *(const float4*)s0, o = *(const float4*)(s0 + 1024);
            i4v w;
            w[0] = (int)((unsigned)f2b(e.x) | ((unsigned)f2b(o.x) << 16));
            w[1] = (int)((unsigned)f2b(e.y) | ((unsigned)f2b(o.y) << 16));
            w[2] = (int)((unsigned)f2b(e.z) | ((unsigned)f2b(o.z) << 16));
            w[3] = (int)((unsigned)f2b(e.w) | ((unsigned)f2b(o.w) << 16));
            *(i4v*)(vout + pr * 256 + c16v * 8) = w;
        }
    } else {
        int s0r = (t - 64) * 64;
#pragma unroll
        for (int i = 0; i < 4; i++) {
            int c = tid + i * 256; int r = c >> 4, c16 = c & 15;
            int rs = rho(r);
            int cc = c16 ^ (rs & 7);
            s8v v = *(const s8v*)(kb + ((size_t)(b * 128 + s0r + r) * 8 + hk) * 128 + cc * 8);
            *(s8v*)(kout + rs * 128 + c16 * 8) = v;
        }
#pragma unroll
        for (int i = 0; i < 4; i++) {
            int c = tid + i * 256; int pr = c >> 5, c16v = c & 31;
            int nc = c16v ^ pr;
            int n = nc * 4;
            const u16* s0 = vb + ((size_t)(b * 128 + s0r + pr * 2) * 8 + hk) * 128 + n;
            ushort4 e = *(const ushort4*)s0, o = *(const ushort4*)(s0 + 1024);
            i4v w;
            w[0] = (int)((unsigned)e.x | ((unsigned)o.x << 16));
            w[1] = (int)((unsigned)e.y | ((unsigned)o.y << 16));
            w[2] = (int)((unsigned)e.z | ((unsigned)o.z << 16));
            w[3] = (int)((unsigned)e.w | ((unsigned)o.w << 16));
            *(i4v*)(vout + pr * 256 + c16v * 8) = w;
        }
    }
}

// ---------------------------------------------------------------------------
// Flash attention v6 (R10-proven): 32-row KV tiles, swapped-QK in-register
// softmax/PV, defer-rescale, dbuf vmcnt(0)+__syncthreads.
// ---------------------------------------------------------------------------
__global__ __launch_bounds__(256) void fattn6_k(const u16* __restrict__ qb,
                                                const u16* __restrict__ kb2,
                                                const u16* __restrict__ vb2,
                                                const int* __restrict__ cseq,
                                                float* __restrict__ po,
                                                float* __restrict__ mb,
                                                float* __restrict__ lb) {
    __shared__ __align__(16) char Ks[2][8192];
    __shared__ __align__(16) char Vs[2][8192];

    const int tid = threadIdx.x, lane = tid & 63, wid = tid >> 6;
    const int lm = lane & 15, lg = lane >> 4;
    const int bid = blockIdx.x;
    const int sp = bid & 3, half = (bid >> 2) & 1, h = (bid >> 3) & 31, b = bid >> 8;
    const int hk = h >> 2;

    s8v qa[4];
    {
        const u16* qp = qb + ((size_t)((b * 128 + half * 64 + wid * 16 + lm) * 32 + h)) * 128 + lg * 8;
#pragma unroll
        for (int ks = 0; ks < 4; ks++) qa[ks] = *(const s8v*)(qp + ks * 32);
    }

    float m_run = -1e30f, l_run = 0.f;
    f4v acc[8];
#pragma unroll
    for (int dt = 0; dt < 8; dt++) acc[dt] = (f4v){0.f, 0.f, 0.f, 0.f};

    const int cl = cseq[b];
    const int ntc = (cl + 31) >> 5;
    const int tlo = (ntc * sp) >> 2, thi = (ntc * (sp + 1)) >> 2;
    const int ncache = thi - tlo;
    const int ntiles = ncache + (sp == 3 ? 4 : 0);

    const char* gk = (const char*)kb2 + (size_t)(b * 8 + hk) * 66 * 16384;
    const char* gv = (const char*)vb2 + (size_t)(b * 8 + hk) * 66 * 16384;

    auto STAGE = [&](int buf, int gt) {
        const char* gkt = gk + (size_t)gt * 8192 + tid * 16;
        const char* gvt = gv + (size_t)gt * 8192 + tid * 16;
        char* lk = Ks[buf] + tid * 16;
        char* lv = Vs[buf] + tid * 16;
        glds16(gkt, lk);
        glds16(gkt + 4096, lk + 4096);
        glds16(gvt, lv);
        glds16(gvt + 4096, lv + 4096);
    };
    auto GT = [&](int ii) { return ii < ncache ? tlo + ii : 128 + (ii - ncache); };

    if (ntiles > 0) STAGE(0, GT(0));
    asm volatile("s_waitcnt vmcnt(0)" ::: "memory");
    __syncthreads();

    for (int ii = 0; ii < ntiles; ++ii) {
        const int cur = ii & 1;
        if (ii + 1 < ntiles) STAGE(cur ^ 1, GT(ii + 1));
        const int gt = GT(ii);
        const int t0 = gt * 32;

        f4v sc[2];
#pragma unroll
        for (int ct = 0; ct < 2; ct++) sc[ct] = (f4v){0.f, 0.f, 0.f, 0.f};
        __builtin_amdgcn_s_setprio(1);
#pragma unroll
        for (int ct = 0; ct < 2; ct++) {
#pragma unroll
            for (int ks = 0; ks < 4; ks++) {
                int r = ct * 16 + lm;
                s8v kf = *(const s8v*)(Ks[cur] + ((r * 256 + ks * 64 + lg * 16) ^ ((r & 7) << 4)));
                sc[ct] = __builtin_amdgcn_mfma_f32_16x16x32_bf16(kf, qa[ks], sc[ct], 0, 0, 0);
            }
        }
        __builtin_amdgcn_s_setprio(0);

        if (gt < 128 && (t0 + 32 > cl)) {
#pragma unroll
            for (int ct = 0; ct < 2; ct++)
#pragma unroll
                for (int r = 0; r < 4; r++) {
                    int kvloc = lg * 8 + ct * 4 + r;
                    if (t0 + kvloc >= cl) sc[ct][r] = -1e30f;
                }
        }

        float mt = fmaxf(fmaxf(fmaxf(sc[0][0], sc[0][1]), fmaxf(sc[0][2], sc[0][3])),
                         fmaxf(fmaxf(sc[1][0], sc[1][1]), fmaxf(sc[1][2], sc[1][3])));
        mt = fmaxf(mt, __shfl_xor(mt, 16));
        mt = fmaxf(mt, __shfl_xor(mt, 32));

        if (__any(mt > m_run + 12.0f)) {
            float mn = fmaxf(m_run, mt);
            float corr = exp2f(m_run - mn);
            m_run = mn;
            l_run *= corr;
            float c0 = __shfl(corr, lg * 4 + 0);
            float c1 = __shfl(corr, lg * 4 + 1);
            float c2 = __shfl(corr, lg * 4 + 2);
            float c3 = __shfl(corr, lg * 4 + 3);
#pragma unroll
            for (int dt = 0; dt < 8; dt++) {
                acc[dt][0] *= c0; acc[dt][1] *= c1;
                acc[dt][2] *= c2; acc[dt][3] *= c3;
            }
        }

        short pb[2][4];
        float ladd = 0.f;
#pragma unroll
        for (int ct = 0; ct < 2; ct++)
#pragma unroll
            for (int r = 0; r < 4; r++) {
                float pv = exp2f(sc[ct][r] - m_run);
                ladd += pv;
                pb[ct][r] = (short)f2b(pv);
            }
        l_run += ladd;

        __builtin_amdgcn_s_setprio(1);
        {
            s8v pa;
#pragma unroll
            for (int j = 0; j < 4; j++) { pa[j] = pb[0][j]; pa[4 + j] = pb[1][j]; }
            const int pko = (gt & 1) << 4;
#pragma unroll
            for (int dt = 0; dt < 8; dt++) {
                i4v vv;
#pragma unroll
                for (int t = 0; t < 4; t++) {
                    int p = lg * 4 + t;
                    vv[t] = *(const int*)(Vs[cur] + p * 512 + ((((dt * 16 + lm) * 4)) ^ (((p + pko) & 31) << 4)));
                }
                union { i4v i; s8v s; } u; u.i = vv;
                acc[dt] = __builtin_amdgcn_mfma_f32_16x16x32_bf16(pa, u.s, acc[dt], 0, 0, 0);
            }
        }
        __builtin_amdgcn_s_setprio(0);

        asm volatile("s_waitcnt vmcnt(0)" ::: "memory");
        __syncthreads();
    }

#pragma unroll
    for (int dt = 0; dt < 8; dt++) {
#pragma unroll
        for (int r = 0; r < 4; r++) {
            int row = wid * 16 + lg * 4 + r;
            po[((size_t)bid * 64 + row) * 128 + dt * 16 + lm] = acc[dt][r];
        }
    }
    float lt = l_run;
    lt += __shfl_xor(lt, 16);
    lt += __shfl_xor(lt, 32);
    if (lg == 0) {
        mb[(size_t)bid * 64 + wid * 16 + lm] = m_run;
        lb[(size_t)bid * 64 + wid * 16 + lm] = lt;
    }
}

// ---------------------------------------------------------------------------
// Combine 4 splits (exp2-domain weights); emit O in tiled-swizzled A layout.
// ---------------------------------------------------------------------------
__global__ __launch_bounds__(256) void fcomb_k(const float* __restrict__ po,
                                               const float* __restrict__ mb,
                                               const float* __restrict__ lb,
                                               u16* __restrict__ obT) {
    const int pid = blockIdx.x, t = threadIdx.x;
    const int row = t >> 2, dq = t & 3;
    const int half = pid & 1, h = (pid >> 1) & 31, b = pid >> 6;
    float m[4], l[4];
#pragma unroll
    for (int i = 0; i < 4; i++) {
        m[i] = mb[(size_t)(pid * 4 + i) * 64 + row];
        l[i] = lb[(size_t)(pid * 4 + i) * 64 + row];
    }
    float M = fmaxf(fmaxf(m[0], m[1]), fmaxf(m[2], m[3]));
    float w[4], L = 0.f;
#pragma unroll
    for (int i = 0; i < 4; i++) { w[i] = exp2f(m[i] - M); L += w[i] * l[i]; }
    float invL = 1.0f / L;
    const int arow = b * 128 + half * 64 + row;
    const int mt = arow >> 6, rr = arow & 63;
#pragma unroll
    for (int j = 0; j < 8; j++) {
        f4v s = (f4v){0.f, 0.f, 0.f, 0.f};
#pragma unroll
        for (int i = 0; i < 4; i++) {
            f4v a = *(const f4v*)(po + ((size_t)(pid * 4 + i) * 64 + row) * 128 + dq * 32 + j * 4);
            s += w[i] * a;
        }
        ushort4 o;
        o.x = f2b(s[0] * invL); o.y = f2b(s[1] * invL);
        o.z = f2b(s[2] * invL); o.w = f2b(s[3] * invL);
        const int acol = h * 128 + dq * 32 + j * 4;
        const int kt = acol >> 6, cch = (acol >> 3) & 7, wo = acol & 7;
        *(ushort4*)(obT + ((size_t)(mt * 64 + kt)) * 4096 + rr * 64 + ((cch ^ (rr & 7)) * 8) + wo) = o;
    }
}

// ---------------------------------------------------------------------------
extern "C" void kernel_launch(void* const* d_in, const int* in_sizes, int n_in,
                              void* d_out, int out_size, void* d_ws, size_t ws_size,
                              hipStream_t stream) {
    const float* x   = (const float*)d_in[0];
    const float* Wq  = (const float*)d_in[1];
    const float* Wk  = (const float*)d_in[2];
    const float* Wv  = (const float*)d_in[3];
    const float* Wo  = (const float*)d_in[4];
    const float* qnw = (const float*)d_in[5];
    const float* knw = (const float*)d_in[6];
    const float* kc  = (const float*)d_in[7];
    const float* vc  = (const float*)d_in[8];
    const int* btab  = (const int*)d_in[9];
    const int* cseq  = (const int*)d_in[10];
    float* out = (float*)d_out;

    char* ws = (char*)d_ws;
    u16*   qb   = (u16*)(ws + 0);            // 4 MB
    u16*   kb   = (u16*)(ws + 4194304);      // 1 MB
    u16*   vb   = (u16*)(ws + 5242880);      // 1 MB
    u16*   obT  = (u16*)(ws + 6291456);      // 4 MB: xb -> obT
    u16*   xb   = (u16*)(ws + 6291456);
    float* mbuf = (float*)(ws + 10485760);   // 256 KB
    float* lbuf = (float*)(ws + 10747904);   // 256 KB
    float* P    = (float*)(ws + 11010048);   // 32 MB: QKV partials -> po -> Wo partials
    u16*   wW   = (u16*)(ws + 44564480);     // 48 MB wQKV / 32 MB wWo / kb2
    u16*   kb2  = (u16*)(ws + 44564480);     // 34.6 MB (after wQKV dead)
    u16*   vb2  = (u16*)(ws + 79167488);     // 34.6 MB, ends at 113,770,496

    dim3 blk(256, 1, 1);

    tc_k<64><<<dim3(16, 8, 1), blk, 0, stream>>>(x, xb, 4096);
    tc3_k<<<dim3(32, 48, 1), blk, 0, stream>>>(Wq, Wk, Wv, wW);
    fgemm2<<<dim3(768, 1, 1), blk, 0, stream>>>(xb, wW, P, 512, 6144, 4096, 2048, 8, 2);
    epi_k<<<dim3(6144, 1, 1), blk, 0, stream>>>(P, qb, kb, vb, qnw, knw, cseq);

    cvtkv_k<<<dim3(66, 8, 4), blk, 0, stream>>>(kc, vc, kb, vb, btab, cseq, kb2, vb2);
    fattn6_k<<<dim3(1024, 1, 1), blk, 0, stream>>>(qb, kb2, vb2, cseq, P, mbuf, lbuf);
    fcomb_k<<<dim3(256, 1, 1), blk, 0, stream>>>(P, mbuf, lbuf, obT);

    tc_k<128><<<dim3(32, 32, 1), blk, 0, stream>>>(Wo, wW, 4096);
    fgemm2<<<dim3(512, 1, 1), blk, 0, stream>>>(obT, wW, P, 512, 4096, 4096, 2048, 8, 2);
    redN_k<<<dim3(2048, 1, 1), blk, 0, stream>>>(P, out, 2097152, 2, (size_t)512 * 4096);
}

// Round 16
// 212.127 us; speedup vs baseline: 1.0647x; 1.0647x over previous
//
#include <hip/hip_runtime.h>

typedef unsigned short u16;
typedef float f4v __attribute__((ext_vector_type(4)));
typedef short s8v __attribute__((ext_vector_type(8)));
typedef int   i4v __attribute__((ext_vector_type(4)));

#define SCALE_ 0.08838834764831845f
#define LOG2E_ 1.44269504088896340f

__device__ __forceinline__ u16 f2b(float f) {
    union { float f; unsigned u; } c; c.f = f;
    unsigned u = c.u + 0x7fffu + ((c.u >> 16) & 1u);
    return (u16)(u >> 16);
}

__device__ __forceinline__ s8v pack8(float4 a, float4 b) {
    s8v v;
    v[0] = (short)f2b(a.x); v[1] = (short)f2b(a.y);
    v[2] = (short)f2b(a.z); v[3] = (short)f2b(a.w);
    v[4] = (short)f2b(b.x); v[5] = (short)f2b(b.y);
    v[6] = (short)f2b(b.z); v[7] = (short)f2b(b.w);
    return v;
}

typedef const __attribute__((address_space(1))) unsigned int gu32;
typedef __attribute__((address_space(3))) unsigned int lu32;
__device__ __forceinline__ void glds16(const void* g, void* l) {
    __builtin_amdgcn_global_load_lds((gu32*)g, (lu32*)l, 16, 0, 0);
}

// K-row permutation for swapped-QK in-register PV fragments (R6-proven).
__device__ __forceinline__ int rho(int kv) {
    return (kv & 0x20) | ((kv & 0x04) << 2) | ((kv & 0x18) >> 1) | (kv & 3);
}

// ---------------------------------------------------------------------------
// fp32 [N][K] -> bf16 tiled-swizzled [N/RB][K/64][RB][64]. (R11-proven form;
// measured at the mixed-R/W copy roofline ~3.05 TB/s summed traffic.)
// ---------------------------------------------------------------------------
template <int RB>
__global__ __launch_bounds__(256) void wcvt_k(const float* __restrict__ src,
                                              u16* __restrict__ dst, int K) {
    const int kt = blockIdx.x, nt = blockIdx.y;
    u16* out = dst + ((size_t)nt * gridDim.x + kt) * (RB * 64);
#pragma unroll
    for (int i = 0; i < RB / 32; i++) {
        int c = threadIdx.x + i * 256;
        int r = c >> 3, c16 = c & 7, cc = c16 ^ (r & 7);
        const float* p = src + (size_t)(nt * RB + r) * K + kt * 64 + cc * 8;
        float4 f0 = *(const float4*)p, f1 = *(const float4*)(p + 4);
        *(s8v*)(out + r * 64 + c16 * 8) = pack8(f0, f1);
    }
}

// Concatenated Wq|Wk|Wv -> one tiled-B buffer (N=6144). (R11-proven form.)
__global__ __launch_bounds__(256) void wcvt3_k(const float* __restrict__ Wq,
                                               const float* __restrict__ Wk,
                                               const float* __restrict__ Wv,
                                               u16* __restrict__ dst, int K) {
    const int kt = blockIdx.x, nt = blockIdx.y;
    const float* src;
    int ln;
    if (nt < 32)      { src = Wq; ln = nt; }
    else if (nt < 40) { src = Wk; ln = nt - 32; }
    else              { src = Wv; ln = nt - 40; }
    u16* out = dst + ((size_t)nt * gridDim.x + kt) * 8192;
#pragma unroll
    for (int i = 0; i < 4; i++) {
        int c = threadIdx.x + i * 256;
        int r = c >> 3, c16 = c & 7, cc = c16 ^ (r & 7);
        const float* p = src + (size_t)(ln * 128 + r) * K + kt * 64 + cc * 8;
        float4 f0 = *(const float4*)p, f1 = *(const float4*)(p + 4);
        *(s8v*)(out + r * 64 + c16 * 8) = pack8(f0, f1);
    }
}

// ---------------------------------------------------------------------------
// GEMM v2 (R6-proven): 2-buffer dbuf, vmcnt(0)+__syncthreads, glds staging,
// XCD-chunked bijective swizzle (1D grid), split-K.
// ---------------------------------------------------------------------------
__global__ __launch_bounds__(256) void fgemm2(const u16* __restrict__ Ag,
                                              const u16* __restrict__ Bg,
                                              float* __restrict__ Cp,
                                              int M, int N, int K, int Ksl,
                                              int NY, int NZ) {
    __shared__ __align__(16) u16 As[2][4096];
    __shared__ __align__(16) u16 Bs[2][8192];
    const int tid = threadIdx.x, lane = tid & 63, wid = tid >> 6;
    const int lm = lane & 15, lg = lane >> 4;
    const int nb = gridDim.x, per = nb >> 3, w = blockIdx.x;
    const int idx = (w & 7) * per + (w >> 3);
    const int nx = idx / (NY * NZ);
    const int rem = idx - nx * (NY * NZ);
    const int my = rem % NY, z = rem / NY;
    const int m0 = my * 64, n0 = nx * 128;
    const int KT = K >> 6, NT = Ksl >> 6;
    const int kt0 = (z * Ksl) >> 6;
    const u16* ga = Ag + ((size_t)my * KT + kt0) * 4096;
    const u16* gb = Bg + ((size_t)nx * KT + kt0) * 8192;
    Cp += (size_t)z * M * N;

    f4v acc[4][2];
#pragma unroll
    for (int mi = 0; mi < 4; mi++)
#pragma unroll
        for (int ni = 0; ni < 2; ni++) acc[mi][ni] = (f4v){0.f, 0.f, 0.f, 0.f};

    auto STAGE = [&](int buf, int kt) {
        const char* a = (const char*)(ga + (size_t)kt * 4096) + tid * 16;
        const char* b = (const char*)(gb + (size_t)kt * 8192) + tid * 16;
        char* la = (char*)As[buf] + tid * 16;
        char* lb = (char*)Bs[buf] + tid * 16;
        glds16(a, la);
        glds16(a + 4096, la + 4096);
#pragma unroll
        for (int i = 0; i < 4; i++) glds16(b + i * 4096, lb + i * 4096);
    };

    STAGE(0, 0);
    asm volatile("s_waitcnt vmcnt(0)" ::: "memory");
    __syncthreads();

    for (int kt = 0; kt < NT; ++kt) {
        const int cur = kt & 1;
        if (kt + 1 < NT) STAGE(cur ^ 1, kt + 1);
#pragma unroll
        for (int ks = 0; ks < 2; ks++) {
            s8v av[4], bv[2];
#pragma unroll
            for (int mi = 0; mi < 4; mi++) {
                int r = mi * 16 + lm;
                av[mi] = *(const s8v*)(As[cur] + r * 64 + (((ks * 4 + lg) ^ (r & 7)) * 8));
            }
#pragma unroll
            for (int ni = 0; ni < 2; ni++) {
                int r = wid * 32 + ni * 16 + lm;
                bv[ni] = *(const s8v*)(Bs[cur] + r * 64 + (((ks * 4 + lg) ^ (r & 7)) * 8));
            }
#pragma unroll
            for (int mi = 0; mi < 4; mi++)
#pragma unroll
                for (int ni = 0; ni < 2; ni++)
                    acc[mi][ni] = __builtin_amdgcn_mfma_f32_16x16x32_bf16(av[mi], bv[ni], acc[mi][ni], 0, 0, 0);
        }
        asm volatile("s_waitcnt vmcnt(0)" ::: "memory");
        __syncthreads();
    }

#pragma unroll
    for (int mi = 0; mi < 4; mi++)
#pragma unroll
        for (int ni = 0; ni < 2; ni++)
#pragma unroll
            for (int r = 0; r < 4; r++) {
                int m = m0 + mi * 16 + lg * 4 + r;
                int n = n0 + wid * 32 + ni * 16 + lm;
                Cp[(size_t)m * N + n] = acc[mi][ni][r];
            }
}

// ---------------------------------------------------------------------------
// Fused epilogue over C[z][512][6144]: Q-norm+rope / K-norm+rope / V convert.
// ---------------------------------------------------------------------------
__global__ __launch_bounds__(256) void epi_k(const float* __restrict__ C,
                                             u16* __restrict__ qb,
                                             u16* __restrict__ kb,
                                             u16* __restrict__ vb,
                                             const float* __restrict__ qnw,
                                             const float* __restrict__ knw,
                                             const int* __restrict__ cseq) {
    const int lane = threadIdx.x & 63, w = threadIdx.x >> 6;
    const int blk = blockIdx.x;
    const size_t sls = (size_t)512 * 6144;

    if (blk < 4096) {           // ---- Q ----
        const int rid = blk * 4 + w;
        const int h = rid & 31, m = rid >> 5;
        const int s = m & 127, b = m >> 7;
        const float* p = C + (size_t)m * 6144 + h * 128;
        float x1 = p[lane] + p[sls + lane];
        float x2 = p[lane + 64] + p[sls + lane + 64];
        float ss = x1 * x1 + x2 * x2;
#pragma unroll
        for (int off = 1; off < 64; off <<= 1) ss += __shfl_xor(ss, off);
        float inv = rsqrtf(ss * (1.0f / 128.0f) + 1e-6f);
        float n1 = x1 * inv * qnw[lane];
        float n2 = x2 * inv * qnw[lane + 64];
        float pos = (float)(cseq[b] + s);
        float ang = pos * powf(10000.0f, -(float)lane * (1.0f / 64.0f));
        float cs = cosf(ang), sn = sinf(ang);
        const float osc = SCALE_ * LOG2E_;
        qb[(size_t)rid * 128 + lane]      = f2b((n1 * cs - n2 * sn) * osc);
        qb[(size_t)rid * 128 + lane + 64] = f2b((n2 * cs + n1 * sn) * osc);
    } else if (blk < 5120) {    // ---- K ----
        const int rid = (blk - 4096) * 4 + w;
        const int hk = rid & 7, m = rid >> 3;
        const int s = m & 127, b = m >> 7;
        const float* p = C + (size_t)m * 6144 + 4096 + hk * 128;
        float x1 = p[lane] + p[sls + lane];
        float x2 = p[lane + 64] + p[sls + lane + 64];
        float ss = x1 * x1 + x2 * x2;
#pragma unroll
        for (int off = 1; off < 64; off <<= 1) ss += __shfl_xor(ss, off);
        float inv = rsqrtf(ss * (1.0f / 128.0f) + 1e-6f);
        float n1 = x1 * inv * knw[lane];
        float n2 = x2 * inv * knw[lane + 64];
        float pos = (float)(cseq[b] + s);
        float ang = pos * powf(10000.0f, -(float)lane * (1.0f / 64.0f));
        float cs = cosf(ang), sn = sinf(ang);
        kb[(size_t)rid * 128 + lane]      = f2b(n1 * cs - n2 * sn);
        kb[(size_t)rid * 128 + lane + 64] = f2b(n2 * cs + n1 * sn);
    } else {                    // ---- V ----
        const int rid = (blk - 5120) * 4 + w;
        const int hk = rid & 7, m = rid >> 3;
        const float* p = C + (size_t)m * 6144 + 5120 + hk * 128;
        float x1 = p[lane] + p[sls + lane];
        float x2 = p[lane + 64] + p[sls + lane + 64];
        vb[(size_t)rid * 128 + lane]      = f2b(x1);
        vb[(size_t)rid * 128 + lane + 64] = f2b(x2);
    }
}

// Sum nsl K-slices -> fp32 out.
__global__ __launch_bounds__(256) void redN_k(const float* __restrict__ p,
                                              float* __restrict__ out, int n4,
                                              int nsl, size_t sls) {
    int i = blockIdx.x * blockDim.x + threadIdx.x;
    if (i < n4) {
        f4v s = (f4v){0.f, 0.f, 0.f, 0.f};
        for (int sl = 0; sl < nsl; sl++)
            s += *(const f4v*)(p + sl * sls + (size_t)i * 4);
        *(f4v*)(out + (size_t)i * 4) = s;
    }
}

// ---------------------------------------------------------------------------
// KV-cache -> bf16 MFMA-ready layouts (K rows rho-permuted). Unchanged (R6).
// ---------------------------------------------------------------------------
__global__ __launch_bounds__(256) void cvtkv_k(const float* __restrict__ kc,
                                               const float* __restrict__ vc,
                                               const u16* __restrict__ kb,
                                               const u16* __restrict__ vb,
                                               const int* __restrict__ btab,
                                               const int* __restrict__ cseq,
                                               u16* __restrict__ kb2,
                                               u16* __restrict__ vb2) {
    const int t = blockIdx.x, hk = blockIdx.y, b = blockIdx.z;
    const int tid = threadIdx.x;
    const int cl = cseq[b];
    if (t < 64 && t * 64 >= cl) return;
    u16* kout = kb2 + ((size_t)(b * 8 + hk) * 66 + t) * 8192;
    u16* vout = vb2 + ((size_t)(b * 8 + hk) * 66 + t) * 8192;

    if (t < 64) {
#pragma unroll
        for (int i = 0; i < 4; i++) {
            int c = tid + i * 256; int r = c >> 4, c16 = c & 15;
            int rs = rho(r);
            int cc = c16 ^ (rs & 7);
            int p = t * 64 + r;
            const float* src = kc + (((size_t)btab[b * 16 + (p >> 8)] * 256 + (p & 255)) * 8 + hk) * 128 + cc * 8;
            float4 f0 = *(const float4*)src, f1 = *(const float4*)(src + 4);
            *(s8v*)(kout + rs * 128 + c16 * 8) = pack8(f0, f1);
        }
#pragma unroll
        for (int i = 0; i < 4; i++) {
            int c = tid + i * 256; int pr = c >> 5, c16v = c & 31;
            int nc = c16v ^ pr;
            int n = nc * 4;
            int p = t * 64 + pr * 2;
            const float* s0 = vc + (((size_t)btab[b * 16 + (p >> 8)] * 256 + (p & 255)) * 8 + hk) * 128 + n;
            float4 e = *(const float4*)s0, o = *(const float4*)(s0 + 1024);
            i4v w;
            w[0] = (int)((unsigned)f2b(e.x) | ((unsigned)f2b(o.x) << 16));
            w[1] = (int)((unsigned)f2b(e.y) | ((unsigned)f2b(o.y) << 16));
            w[2] = (int)((unsigned)f2b(e.z) | ((unsigned)f2b(o.z) << 16));
            w[3] = (int)((unsigned)f2b(e.w) | ((unsigned)f2b(o.w) << 16));
            *(i4v*)(vout + pr * 256 + c16v * 8) = w;
        }
    } else {
        int s0r = (t - 64) * 64;
#pragma unroll
        for (int i = 0; i < 4; i++) {
            int c = tid + i * 256; int r = c >> 4, c16 = c & 15;
            int rs = rho(r);
            int cc = c16 ^ (rs & 7);
            s8v v = *(const s8v*)(kb + ((size_t)(b * 128 + s0r + r) * 8 + hk) * 128 + cc * 8);
            *(s8v*)(kout + rs * 128 + c16 * 8) = v;
        }
#pragma unroll
        for (int i = 0; i < 4; i++) {
            int c = tid + i * 256; int pr = c >> 5, c16v = c & 31;
            int nc = c16v ^ pr;
            int n = nc * 4;
            const u16* s0 = vb + ((size_t)(b * 128 + s0r + pr * 2) * 8 + hk) * 128 + n;
            ushort4 e = *(const ushort4*)s0, o = *(const ushort4*)(s0 + 1024);
            i4v w;
            w[0] = (int)((unsigned)e.x | ((unsigned)o.x << 16));
            w[1] = (int)((unsigned)e.y | ((unsigned)o.y << 16));
            w[2] = (int)((unsigned)e.z | ((unsigned)o.z << 16));
            w[3] = (int)((unsigned)e.w | ((unsigned)o.w << 16));
            *(i4v*)(vout + pr * 256 + c16v * 8) = w;
        }
    }
}

// ---------------------------------------------------------------------------
// Flash attention v6 (R10-proven): 32-row KV tiles, swapped-QK in-register
// softmax/PV, defer-rescale, dbuf vmcnt(0)+__syncthreads.
// ---------------------------------------------------------------------------
__global__ __launch_bounds__(256) void fattn6_k(const u16* __restrict__ qb,
                                                const u16* __restrict__ kb2,
                                                const u16* __restrict__ vb2,
                                                const int* __restrict__ cseq,
                                                float* __restrict__ po,
                                                float* __restrict__ mb,
                                                float* __restrict__ lb) {
    __shared__ __align__(16) char Ks[2][8192];
    __shared__ __align__(16) char Vs[2][8192];

    const int tid = threadIdx.x, lane = tid & 63, wid = tid >> 6;
    const int lm = lane & 15, lg = lane >> 4;
    const int bid = blockIdx.x;
    const int sp = bid & 3, half = (bid >> 2) & 1, h = (bid >> 3) & 31, b = bid >> 8;
    const int hk = h >> 2;

    s8v qa[4];
    {
        const u16* qp = qb + ((size_t)((b * 128 + half * 64 + wid * 16 + lm) * 32 + h)) * 128 + lg * 8;
#pragma unroll
        for (int ks = 0; ks < 4; ks++) qa[ks] = *(const s8v*)(qp + ks * 32);
    }

    float m_run = -1e30f, l_run = 0.f;
    f4v acc[8];
#pragma unroll
    for (int dt = 0; dt < 8; dt++) acc[dt] = (f4v){0.f, 0.f, 0.f, 0.f};

    const int cl = cseq[b];
    const int ntc = (cl + 31) >> 5;
    const int tlo = (ntc * sp) >> 2, thi = (ntc * (sp + 1)) >> 2;
    const int ncache = thi - tlo;
    const int ntiles = ncache + (sp == 3 ? 4 : 0);

    const char* gk = (const char*)kb2 + (size_t)(b * 8 + hk) * 66 * 16384;
    const char* gv = (const char*)vb2 + (size_t)(b * 8 + hk) * 66 * 16384;

    auto STAGE = [&](int buf, int gt) {
        const char* gkt = gk + (size_t)gt * 8192 + tid * 16;
        const char* gvt = gv + (size_t)gt * 8192 + tid * 16;
        char* lk = Ks[buf] + tid * 16;
        char* lv = Vs[buf] + tid * 16;
        glds16(gkt, lk);
        glds16(gkt + 4096, lk + 4096);
        glds16(gvt, lv);
        glds16(gvt + 4096, lv + 4096);
    };
    auto GT = [&](int ii) { return ii < ncache ? tlo + ii : 128 + (ii - ncache); };

    if (ntiles > 0) STAGE(0, GT(0));
    asm volatile("s_waitcnt vmcnt(0)" ::: "memory");
    __syncthreads();

    for (int ii = 0; ii < ntiles; ++ii) {
        const int cur = ii & 1;
        if (ii + 1 < ntiles) STAGE(cur ^ 1, GT(ii + 1));
        const int gt = GT(ii);
        const int t0 = gt * 32;

        f4v sc[2];
#pragma unroll
        for (int ct = 0; ct < 2; ct++) sc[ct] = (f4v){0.f, 0.f, 0.f, 0.f};
        __builtin_amdgcn_s_setprio(1);
#pragma unroll
        for (int ct = 0; ct < 2; ct++) {
#pragma unroll
            for (int ks = 0; ks < 4; ks++) {
                int r = ct * 16 + lm;
                s8v kf = *(const s8v*)(Ks[cur] + ((r * 256 + ks * 64 + lg * 16) ^ ((r & 7) << 4)));
                sc[ct] = __builtin_amdgcn_mfma_f32_16x16x32_bf16(kf, qa[ks], sc[ct], 0, 0, 0);
            }
        }
        __builtin_amdgcn_s_setprio(0);

        if (gt < 128 && (t0 + 32 > cl)) {
#pragma unroll
            for (int ct = 0; ct < 2; ct++)
#pragma unroll
                for (int r = 0; r < 4; r++) {
                    int kvloc = lg * 8 + ct * 4 + r;
                    if (t0 + kvloc >= cl) sc[ct][r] = -1e30f;
                }
        }

        float mt = fmaxf(fmaxf(fmaxf(sc[0][0], sc[0][1]), fmaxf(sc[0][2], sc[0][3])),
                         fmaxf(fmaxf(sc[1][0], sc[1][1]), fmaxf(sc[1][2], sc[1][3])));
        mt = fmaxf(mt, __shfl_xor(mt, 16));
        mt = fmaxf(mt, __shfl_xor(mt, 32));

        if (__any(mt > m_run + 12.0f)) {
            float mn = fmaxf(m_run, mt);
            float corr = exp2f(m_run - mn);
            m_run = mn;
            l_run *= corr;
            float c0 = __shfl(corr, lg * 4 + 0);
            float c1 = __shfl(corr, lg * 4 + 1);
            float c2 = __shfl(corr, lg * 4 + 2);
            float c3 = __shfl(corr, lg * 4 + 3);
#pragma unroll
            for (int dt = 0; dt < 8; dt++) {
                acc[dt][0] *= c0; acc[dt][1] *= c1;
                acc[dt][2] *= c2; acc[dt][3] *= c3;
            }
        }

        short pb[2][4];
        float ladd = 0.f;
#pragma unroll
        for (int ct = 0; ct < 2; ct++)
#pragma unroll
            for (int r = 0; r < 4; r++) {
                float pv = exp2f(sc[ct][r] - m_run);
                ladd += pv;
                pb[ct][r] = (short)f2b(pv);
            }
        l_run += ladd;

        __builtin_amdgcn_s_setprio(1);
        {
            s8v pa;
#pragma unroll
            for (int j = 0; j < 4; j++) { pa[j] = pb[0][j]; pa[4 + j] = pb[1][j]; }
            const int pko = (gt & 1) << 4;
#pragma unroll
            for (int dt = 0; dt < 8; dt++) {
                i4v vv;
#pragma unroll
                for (int t = 0; t < 4; t++) {
                    int p = lg * 4 + t;
                    vv[t] = *(const int*)(Vs[cur] + p * 512 + ((((dt * 16 + lm) * 4)) ^ (((p + pko) & 31) << 4)));
                }
                union { i4v i; s8v s; } u; u.i = vv;
                acc[dt] = __builtin_amdgcn_mfma_f32_16x16x32_bf16(pa, u.s, acc[dt], 0, 0, 0);
            }
        }
        __builtin_amdgcn_s_setprio(0);

        asm volatile("s_waitcnt vmcnt(0)" ::: "memory");
        __syncthreads();
    }

#pragma unroll
    for (int dt = 0; dt < 8; dt++) {
#pragma unroll
        for (int r = 0; r < 4; r++) {
            int row = wid * 16 + lg * 4 + r;
            po[((size_t)bid * 64 + row) * 128 + dt * 16 + lm] = acc[dt][r];
        }
    }
    float lt = l_run;
    lt += __shfl_xor(lt, 16);
    lt += __shfl_xor(lt, 32);
    if (lg == 0) {
        mb[(size_t)bid * 64 + wid * 16 + lm] = m_run;
        lb[(size_t)bid * 64 + wid * 16 + lm] = lt;
    }
}

// ---------------------------------------------------------------------------
// Combine 4 splits (exp2-domain weights); emit O in tiled-swizzled A layout.
// ---------------------------------------------------------------------------
__global__ __launch_bounds__(256) void fcomb_k(const float* __restrict__ po,
                                               const float* __restrict__ mb,
                                               const float* __restrict__ lb,
                                               u16* __restrict__ obT) {
    const int pid = blockIdx.x, t = threadIdx.x;
    const int row = t >> 2, dq = t & 3;
    const int half = pid & 1, h = (pid >> 1) & 31, b = pid >> 6;
    float m[4], l[4];
#pragma unroll
    for (int i = 0; i < 4; i++) {
        m[i] = mb[(size_t)(pid * 4 + i) * 64 + row];
        l[i] = lb[(size_t)(pid * 4 + i) * 64 + row];
    }
    float M = fmaxf(fmaxf(m[0], m[1]), fmaxf(m[2], m[3]));
    float w[4], L = 0.f;
#pragma unroll
    for (int i = 0; i < 4; i++) { w[i] = exp2f(m[i] - M); L += w[i] * l[i]; }
    float invL = 1.0f / L;
    const int arow = b * 128 + half * 64 + row;
    const int mt = arow >> 6, rr = arow & 63;
#pragma unroll
    for (int j = 0; j < 8; j++) {
        f4v s = (f4v){0.f, 0.f, 0.f, 0.f};
#pragma unroll
        for (int i = 0; i < 4; i++) {
            f4v a = *(const f4v*)(po + ((size_t)(pid * 4 + i) * 64 + row) * 128 + dq * 32 + j * 4);
            s += w[i] * a;
        }
        ushort4 o;
        o.x = f2b(s[0] * invL); o.y = f2b(s[1] * invL);
        o.z = f2b(s[2] * invL); o.w = f2b(s[3] * invL);
        const int acol = h * 128 + dq * 32 + j * 4;
        const int kt = acol >> 6, cch = (acol >> 3) & 7, wo = acol & 7;
        *(ushort4*)(obT + ((size_t)(mt * 64 + kt)) * 4096 + rr * 64 + ((cch ^ (rr & 7)) * 8) + wo) = o;
    }
}

// ---------------------------------------------------------------------------
extern "C" void kernel_launch(void* const* d_in, const int* in_sizes, int n_in,
                              void* d_out, int out_size, void* d_ws, size_t ws_size,
                              hipStream_t stream) {
    const float* x   = (const float*)d_in[0];
    const float* Wq  = (const float*)d_in[1];
    const float* Wk  = (const float*)d_in[2];
    const float* Wv  = (const float*)d_in[3];
    const float* Wo  = (const float*)d_in[4];
    const float* qnw = (const float*)d_in[5];
    const float* knw = (const float*)d_in[6];
    const float* kc  = (const float*)d_in[7];
    const float* vc  = (const float*)d_in[8];
    const int* btab  = (const int*)d_in[9];
    const int* cseq  = (const int*)d_in[10];
    float* out = (float*)d_out;

    char* ws = (char*)d_ws;
    u16*   qb   = (u16*)(ws + 0);            // 4 MB
    u16*   kb   = (u16*)(ws + 4194304);      // 1 MB
    u16*   vb   = (u16*)(ws + 5242880);      // 1 MB
    u16*   obT  = (u16*)(ws + 6291456);      // 4 MB: xb -> obT
    u16*   xb   = (u16*)(ws + 6291456);
    float* mbuf = (float*)(ws + 10485760);   // 256 KB
    float* lbuf = (float*)(ws + 10747904);   // 256 KB
    float* P    = (float*)(ws + 11010048);   // 32 MB: QKV partials -> po -> Wo partials
    u16*   wW   = (u16*)(ws + 44564480);     // 48 MB wQKV / 32 MB wWo / kb2
    u16*   kb2  = (u16*)(ws + 44564480);     // 34.6 MB (after wQKV dead)
    u16*   vb2  = (u16*)(ws + 79167488);     // 34.6 MB, ends at 113,770,496

    dim3 blk(256, 1, 1);

    wcvt_k<64><<<dim3(64, 8, 1), blk, 0, stream>>>(x, xb, 4096);
    wcvt3_k<<<dim3(64, 48, 1), blk, 0, stream>>>(Wq, Wk, Wv, wW, 4096);
    fgemm2<<<dim3(768, 1, 1), blk, 0, stream>>>(xb, wW, P, 512, 6144, 4096, 2048, 8, 2);
    epi_k<<<dim3(6144, 1, 1), blk, 0, stream>>>(P, qb, kb, vb, qnw, knw, cseq);

    cvtkv_k<<<dim3(66, 8, 4), blk, 0, stream>>>(kc, vc, kb, vb, btab, cseq, kb2, vb2);
    fattn6_k<<<dim3(1024, 1, 1), blk, 0, stream>>>(qb, kb2, vb2, cseq, P, mbuf, lbuf);
    fcomb_k<<<dim3(256, 1, 1), blk, 0, stream>>>(P, mbuf, lbuf, obT);

    wcvt_k<128><<<dim3(64, 32, 1), blk, 0, stream>>>(Wo, wW, 4096);
    fgemm2<<<dim3(512, 1, 1), blk, 0, stream>>>(obT, wW, P, 512, 4096, 4096, 2048, 8, 2);
    redN_k<<<dim3(2048, 1, 1), blk, 0, stream>>>(P, out, 2097152, 2, (size_t)512 * 4096);
}